// Round 9
// baseline (6245.192 us; speedup 1.0000x reference)
//
#include <hip/hip_runtime.h>

#define DI __device__ __forceinline__

typedef short s16x8 __attribute__((ext_vector_type(8)));
typedef float f32x4 __attribute__((ext_vector_type(4)));

typedef __attribute__((address_space(1))) const unsigned int as1_cuint;
typedef __attribute__((address_space(3))) unsigned int as3_uint;

DI unsigned short f2bf(float f) {
  union { float f; unsigned int u; } v; v.f = f;
  unsigned int r = v.u + 0x7fffu + ((v.u >> 16) & 1u);
  return (unsigned short)(r >> 16);
}
DI float bf2f(unsigned short b) {
  union { unsigned int u; float f; } v; v.u = ((unsigned int)b) << 16;
  return v.f;
}

DI void gl_lds16(const void* g, void* l) {
  __builtin_amdgcn_global_load_lds((as1_cuint*)g, (as3_uint*)l, 16, 0, 0);
}

DI void bar() {
  __builtin_amdgcn_sched_barrier(0);
  __builtin_amdgcn_s_barrier();
  __builtin_amdgcn_sched_barrier(0);
}
DI void vm0() { asm volatile("s_waitcnt vmcnt(0)" ::: "memory"); }

#define MFMA __builtin_amdgcn_mfma_f32_16x16x32_bf16

// ---------------- fp32 -> bf16 convert ----------------
__global__ __launch_bounds__(256) void cvt_f32_bf16(const float* __restrict__ src,
                                                    unsigned short* __restrict__ dst, int n4) {
  int i = blockIdx.x * blockDim.x + threadIdx.x;
  int stride = gridDim.x * blockDim.x;
  for (; i < n4; i += stride) {
    float4 v = ((const float4*)src)[i];
    ((ushort4*)dst)[i] = make_ushort4(f2bf(v.x), f2bf(v.y), f2bf(v.z), f2bf(v.w));
  }
}

// ---------------- dual RMSNorm ----------------
__global__ __launch_bounds__(256) void rmsnorm_dual(const float* __restrict__ hs,
                                                    const float* __restrict__ w1,
                                                    const float* __restrict__ w2,
                                                    unsigned short* __restrict__ xo,
                                                    unsigned short* __restrict__ ho) {
  const int D = 2048;
  int t = blockIdx.x, tid = threadIdx.x;
  const float* row = hs + (size_t)t * D;
  float4 a = ((const float4*)row)[tid * 2];
  float4 b = ((const float4*)row)[tid * 2 + 1];
  float ss = a.x * a.x + a.y * a.y + a.z * a.z + a.w * a.w +
             b.x * b.x + b.y * b.y + b.z * b.z + b.w * b.w;
#pragma unroll
  for (int off = 32; off; off >>= 1) ss += __shfl_xor(ss, off);
  __shared__ float red[4];
  int wave = tid >> 6, lane = tid & 63;
  if (lane == 0) red[wave] = ss;
  __syncthreads();
  float tot = red[0] + red[1] + red[2] + red[3];
  float inv = rsqrtf(tot / (float)D + 1e-6f);
  int base = tid * 8;
  float vals[8] = {a.x, a.y, a.z, a.w, b.x, b.y, b.z, b.w};
  float4 w1a = ((const float4*)(w1 + base))[0];
  float4 w1b = ((const float4*)(w1 + base))[1];
  float4 w2a = ((const float4*)(w2 + base))[0];
  float4 w2b = ((const float4*)(w2 + base))[1];
  float w1v[8] = {w1a.x, w1a.y, w1a.z, w1a.w, w1b.x, w1b.y, w1b.z, w1b.w};
  float w2v[8] = {w2a.x, w2a.y, w2a.z, w2a.w, w2b.x, w2b.y, w2b.z, w2b.w};
  unsigned short ox[8], oh[8];
#pragma unroll
  for (int j = 0; j < 8; ++j) {
    float n = vals[j] * inv;
    ox[j] = f2bf(n * w1v[j]);
    oh[j] = f2bf(n * w2v[j]);
  }
  ushort4* xp = (ushort4*)(xo + (size_t)t * D + base);
  ushort4* hp = (ushort4*)(ho + (size_t)t * D + base);
  xp[0] = make_ushort4(ox[0], ox[1], ox[2], ox[3]);
  xp[1] = make_ushort4(ox[4], ox[5], ox[6], ox[7]);
  hp[0] = make_ushort4(oh[0], oh[1], oh[2], oh[3]);
  hp[1] = make_ushort4(oh[4], oh[5], oh[6], oh[7]);
}

// ======== single-buffer multi-block GEMM: C[MW*64 x 128] = A @ Bt^T ========
// MW=4: 512thr/8 waves (4M x 2N), LDS 48KB -> 3 blocks/CU.
// MW=2: 256thr/4 waves (2M x 2N), LDS 32KB -> 4 blocks/CU.
// Wave tile 64x64 (acc 64). Loop: bar; stage; vm0; bar; frags+MFMA.
// Cross-block overlap hides the stage/drain phase (m97/m114 mechanism).
#define E_NONE 0
#define E_RES 3

template <int EPI, int MW>
__global__ __launch_bounds__(MW * 128, MW == 4 ? 6 : 4) void gemm_sb(
    const unsigned short* __restrict__ Amat, const unsigned short* __restrict__ Bt,
    int N, int K, int NT,
    unsigned short* __restrict__ Cbf, float* __restrict__ Cf,
    const float* __restrict__ Res) {
  __shared__ __align__(16) unsigned short lds[(MW + 2) * 4096];
  const int THREADS = MW * 128;
  const int NLD = (MW + 2) * 4 / MW;  // gl_lds16 per thread per tile
  int tid = threadIdx.x, lane = tid & 63;
  int w = tid >> 6, wm = w >> 1, wn = w & 1;
  int lr = lane & 15, g = lane >> 4;
  int nbn = N >> 7, nwg = gridDim.x, wg = blockIdx.x;
  int cpx = nwg >> 3;
  int swz = (wg & 7) * cpx + (wg >> 3);
  int tm = swz / nbn, tn = swz - tm * nbn;
  size_t m0 = (size_t)tm * (MW * 64), n0 = (size_t)tn * 128;

  // hoisted frag byte offsets (A region [0, MW*8192)B, B region [MW*8192, ...))
  int boffA[4][2], boffB[4][2];
#pragma unroll
  for (int mi = 0; mi < 4; ++mi)
#pragma unroll
    for (int kh = 0; kh < 2; ++kh) {
      int row = wm * 64 + mi * 16 + lr;
      boffA[mi][kh] = row * 128 + ((kh * 64 + g * 16) ^ ((row & 7) << 4));
    }
#pragma unroll
  for (int ni = 0; ni < 4; ++ni)
#pragma unroll
    for (int kh = 0; kh < 2; ++kh) {
      int row = wn * 64 + ni * 16 + lr;
      boffB[ni][kh] = MW * 8192 + row * 128 + ((kh * 64 + g * 16) ^ ((row & 7) << 4));
    }
  const char* ldsb = (const char*)lds;

  // hoisted staging pointers: chunk c = i*THREADS + tid (16B each), linear LDS dest,
  // inverse-swizzled global source (rule #21).
  const unsigned short* sp[NLD];
#pragma unroll
  for (int i = 0; i < NLD; ++i) {
    int c = i * THREADS + tid;
    int row = c >> 3, cb = (c & 7) * 16;
    const unsigned short* gb;
    size_t r0;
    int lrow;
    if (i < 4) { gb = Amat; r0 = m0; lrow = row; }
    else       { gb = Bt;   r0 = n0; lrow = row - MW * 64; }
    int scb = cb ^ ((lrow & 7) << 4);
    sp[i] = gb + (r0 + lrow) * (size_t)K + (scb >> 1);
  }

  f32x4 acc[4][4] = {};

  for (int t = 0; t < NT; ++t) {
    bar();  // all waves done reading previous tile
#pragma unroll
    for (int i = 0; i < NLD; ++i) {
      gl_lds16(sp[i], &lds[i * THREADS * 8 + w * 512]);
      sp[i] += 64;
    }
    vm0();
    bar();
    s16x8 afr[4][2], bfr[4][2];
#pragma unroll
    for (int mi = 0; mi < 4; ++mi)
#pragma unroll
      for (int kh = 0; kh < 2; ++kh)
        afr[mi][kh] = *(const s16x8*)(ldsb + boffA[mi][kh]);
#pragma unroll
    for (int ni = 0; ni < 4; ++ni)
#pragma unroll
      for (int kh = 0; kh < 2; ++kh)
        bfr[ni][kh] = *(const s16x8*)(ldsb + boffB[ni][kh]);
    __builtin_amdgcn_s_setprio(1);
#pragma unroll
    for (int mi = 0; mi < 4; ++mi)
#pragma unroll
      for (int ni = 0; ni < 4; ++ni)
#pragma unroll
        for (int kh = 0; kh < 2; ++kh)
          acc[mi][ni] = MFMA(afr[mi][kh], bfr[ni][kh], acc[mi][ni], 0, 0, 0);
    __builtin_amdgcn_s_setprio(0);
  }

#pragma unroll
  for (int mi = 0; mi < 4; ++mi)
#pragma unroll
    for (int r = 0; r < 4; ++r) {
      size_t row = m0 + wm * 64 + mi * 16 + g * 4 + r;
#pragma unroll
      for (int ni = 0; ni < 4; ++ni) {
        size_t col = n0 + wn * 64 + ni * 16 + lr;
        float v = acc[mi][ni][r];
        if constexpr (EPI == E_RES) Cf[row * N + col] = Res[row * N + col] + v;
        else Cbf[row * N + col] = f2bf(v);
      }
    }
}

// ===== single-buffer fused MLP: Out = silu(H@Wg^T + c@Bsm) * (H@Wu^T) =====
// BM=256, BK=64, 512thr/8 waves (2M x 4N), wave tile 128x32 per matrix (acc 128).
// LDS 64KB single buffer -> 2 blocks/CU. Layout: A[0,32K)B, Bg[32K,48K), Bu[48K,64K).
__global__ __launch_bounds__(512, 4) void gemm_mlp_sb(
    const unsigned short* __restrict__ Hm, const unsigned short* __restrict__ Wg,
    const unsigned short* __restrict__ Wu,
    const float* __restrict__ cvec, const float* __restrict__ Bsm,
    unsigned short* __restrict__ Out) {
  const int N = 8192, K = 2048, NT = 32;
  __shared__ __align__(16) unsigned short lds[32768];
  int tid = threadIdx.x, lane = tid & 63;
  int w = tid >> 6, wm = w >> 2, wn = w & 3;
  int lr = lane & 15, g = lane >> 4;
  int nbn = N >> 7, nwg = gridDim.x, wg = blockIdx.x;
  int cpx = nwg >> 3;
  int swz = (wg & 7) * cpx + (wg >> 3);
  int tm = swz / nbn, tn = swz - tm * nbn;
  size_t m0 = (size_t)tm * 256, n0 = (size_t)tn * 128;

  int boffA[8][2], boffBg[2][2], boffBu[2][2];
#pragma unroll
  for (int mi = 0; mi < 8; ++mi)
#pragma unroll
    for (int kh = 0; kh < 2; ++kh) {
      int row = wm * 128 + mi * 16 + lr;
      boffA[mi][kh] = row * 128 + ((kh * 64 + g * 16) ^ ((row & 7) << 4));
    }
#pragma unroll
  for (int ni = 0; ni < 2; ++ni)
#pragma unroll
    for (int kh = 0; kh < 2; ++kh) {
      int row = wn * 32 + ni * 16 + lr;
      int sz = row * 128 + ((kh * 64 + g * 16) ^ ((row & 7) << 4));
      boffBg[ni][kh] = 32768 + sz;
      boffBu[ni][kh] = 49152 + sz;
    }
  const char* ldsb = (const char*)lds;

  // staging: 4096 chunks of 16B; i<4 -> A (rows 0..255), i=4,5 -> Bg, i=6,7 -> Bu
  const unsigned short* sp[8];
#pragma unroll
  for (int i = 0; i < 8; ++i) {
    int c = i * 512 + tid;
    const unsigned short* gb;
    size_t r0;
    int lrow;
    if (i < 4)      { gb = Hm; r0 = m0; lrow = c >> 3; }
    else if (i < 6) { gb = Wg; r0 = n0; lrow = (c - 2048) >> 3; }
    else            { gb = Wu; r0 = n0; lrow = (c - 3072) >> 3; }
    int cb = (c & 7) * 16;
    int scb = cb ^ ((lrow & 7) << 4);
    sp[i] = gb + (r0 + lrow) * (size_t)K + (scb >> 1);
  }

  f32x4 ag[8][2] = {}, au[8][2] = {};

  for (int t = 0; t < NT; ++t) {
    bar();
#pragma unroll
    for (int i = 0; i < 8; ++i) {
      gl_lds16(sp[i], &lds[i * 4096 + w * 512]);
      sp[i] += 64;
    }
    vm0();
    bar();
    s16x8 afr[8][2], bg[2][2], bu[2][2];
#pragma unroll
    for (int mi = 0; mi < 8; ++mi)
#pragma unroll
      for (int kh = 0; kh < 2; ++kh)
        afr[mi][kh] = *(const s16x8*)(ldsb + boffA[mi][kh]);
#pragma unroll
    for (int ni = 0; ni < 2; ++ni)
#pragma unroll
      for (int kh = 0; kh < 2; ++kh) {
        bg[ni][kh] = *(const s16x8*)(ldsb + boffBg[ni][kh]);
        bu[ni][kh] = *(const s16x8*)(ldsb + boffBu[ni][kh]);
      }
    __builtin_amdgcn_s_setprio(1);
#pragma unroll
    for (int mi = 0; mi < 8; ++mi)
#pragma unroll
      for (int ni = 0; ni < 2; ++ni)
#pragma unroll
        for (int kh = 0; kh < 2; ++kh) {
          ag[mi][ni] = MFMA(afr[mi][kh], bg[ni][kh], ag[mi][ni], 0, 0, 0);
          au[mi][ni] = MFMA(afr[mi][kh], bu[ni][kh], au[mi][ni], 0, 0, 0);
        }
    __builtin_amdgcn_s_setprio(0);
  }

  // epilogue: c-tile 256x16 f32 (16KB, in A region) + Bsm 16x128 f32 (8KB, in Bg region)
  bar();
  float* cl = (float*)lds;
  float* bl = (float*)&lds[16384];
#pragma unroll
  for (int j = 0; j < 2; ++j) {
    int fi = tid * 2 + j;
    ((float4*)cl)[fi] = ((const float4*)(cvec + m0 * 16))[fi];
  }
  {
    int fi = tid;
    ((float4*)bl)[fi] = *(const float4*)(Bsm + (size_t)(fi >> 5) * N + n0 + (fi & 31) * 4);
  }
  bar();

#pragma unroll
  for (int mi = 0; mi < 8; ++mi)
#pragma unroll
    for (int r = 0; r < 4; ++r) {
      int rr = wm * 128 + mi * 16 + g * 4 + r;
      size_t row = m0 + rr;
#pragma unroll
      for (int ni = 0; ni < 2; ++ni) {
        int cc = wn * 32 + ni * 16 + lr;
        size_t col = n0 + cc;
        float s = 0.f;
#pragma unroll
        for (int jj = 0; jj < 16; ++jj) s += cl[rr * 16 + jj] * bl[jj * 128 + cc];
        float gg = ag[mi][ni][r] + s;
        float sig = 1.f / (1.f + __expf(-gg));
        Out[row * N + col] = f2bf(gg * sig * au[mi][ni][r]);
      }
    }
}

// ---------- V transpose: vT[bh][d][k] ----------
__global__ __launch_bounds__(256) void vtrans(const unsigned short* __restrict__ qkv,
                                              unsigned short* __restrict__ vT) {
  __shared__ unsigned short t[64][72];
  int bh = blockIdx.z, b = bh >> 4, h = bh & 15;
  int k0 = blockIdx.x * 64, d0 = blockIdx.y * 64;
  int tid = threadIdx.x;
#pragma unroll
  for (int j = 0; j < 2; ++j) {
    int idx = tid + j * 256;
    int r = idx >> 3, c8 = (idx & 7) * 8;
    s16x8 v = *(const s16x8*)(qkv + ((size_t)(b * 2048 + k0 + r)) * 6144 + 4096 + h * 128 + d0 + c8);
#pragma unroll
    for (int e = 0; e < 8; ++e) t[r][c8 + e] = (unsigned short)v[e];
  }
  __syncthreads();
#pragma unroll
  for (int j = 0; j < 2; ++j) {
    int idx = tid + j * 256;
    int dr = idx >> 3, k8 = (idx & 7) * 8;
    s16x8 o;
#pragma unroll
    for (int e = 0; e < 8; ++e) o[e] = (short)t[k8 + e][dr];
    *(s16x8*)(vT + (size_t)bh * 262144 + (size_t)(d0 + dr) * 2048 + k0 + k8) = o;
  }
}

// ---------- causal flash attention: KVBLK=64, vT staging, balanced pair-pass ----------
__global__ __launch_bounds__(256, 2) void attn_fwd2(const unsigned short* __restrict__ qkv,
                                                    const unsigned short* __restrict__ vT,
                                                    unsigned short* __restrict__ attn) {
  const int LD = 6144;
  __shared__ __align__(16) unsigned short Kt[8192];
  __shared__ __align__(16) unsigned short Vt[8192];
  __shared__ __align__(16) unsigned short Pl[4096];
  int tid = threadIdx.x, w = tid >> 6, lane = tid & 63;
  int lrow = lane & 15, g = lane >> 4;
  int qp = blockIdx.x, bh = blockIdx.y, b = bh >> 4, h = bh & 15;
  const unsigned short* Qb = qkv + (size_t)b * 2048 * LD + h * 128;
  const unsigned short* Kb = Qb + 2048;
  const unsigned short* vTb = vT + (size_t)bh * 262144;
  const float scale = 0.08838834764831845f;

#pragma unroll
  for (int pass = 0; pass < 2; ++pass) {
    int qtile = pass ? (31 - qp) : qp;
    int wq0 = qtile * 64 + w * 16;
    s16x8 qf[4];
#pragma unroll
    for (int kc = 0; kc < 4; ++kc)
      qf[kc] = *(const s16x8*)(Qb + (size_t)(wq0 + lrow) * LD + kc * 32 + g * 8);
    f32x4 ao[8] = {};
    float m_r[4], l_r[4];
#pragma unroll
    for (int r = 0; r < 4; ++r) { m_r[r] = -1e30f; l_r[r] = 0.f; }
    int nkt = qtile + 1;

    for (int kt = 0; kt < nkt; ++kt) {
      int k0 = kt * 64;
      bar();
#pragma unroll
      for (int j = 0; j < 4; ++j) {
        int o = j * 4096 + tid * 16;
        int row = o >> 8, cb = o & 255;
        int scb = cb ^ ((row & 7) << 4);
        gl_lds16(Kb + (size_t)(k0 + row) * LD + (scb >> 1), &Kt[(j * 4096 + w * 1024) >> 1]);
      }
#pragma unroll
      for (int j = 0; j < 4; ++j) {
        int o = j * 4096 + tid * 16;
        int row = o >> 7, cb = o & 127;
        int scb = cb ^ ((row & 7) << 4);
        gl_lds16(vTb + (size_t)row * 2048 + k0 + (scb >> 1), &Vt[(j * 4096 + w * 1024) >> 1]);
      }
      vm0();
      bar();
      f32x4 sa[4] = {};
#pragma unroll
      for (int ni = 0; ni < 4; ++ni)
#pragma unroll
        for (int kc = 0; kc < 4; ++kc) {
          int row = ni * 16 + lrow;
          int cb = kc * 64 + g * 16;
          int scb = cb ^ ((row & 7) << 4);
          s16x8 kf = *(const s16x8*)&Kt[row * 128 + (scb >> 1)];
          sa[ni] = MFMA(qf[kc], kf, sa[ni], 0, 0, 0);
        }
      if (k0 + 63 > wq0) {
#pragma unroll
        for (int ni = 0; ni < 4; ++ni)
#pragma unroll
          for (int r = 0; r < 4; ++r) {
            int q_idx = wq0 + g * 4 + r, k_idx = k0 + ni * 16 + lrow;
            float sv = sa[ni][r] * scale;
            sa[ni][r] = (k_idx > q_idx) ? -1e30f : sv;
          }
      } else {
#pragma unroll
        for (int ni = 0; ni < 4; ++ni)
#pragma unroll
          for (int r = 0; r < 4; ++r) sa[ni][r] *= scale;
      }
      float mt[4];
#pragma unroll
      for (int r = 0; r < 4; ++r)
        mt[r] = fmaxf(fmaxf(sa[0][r], sa[1][r]), fmaxf(sa[2][r], sa[3][r]));
#pragma unroll
      for (int r = 0; r < 4; ++r)
#pragma unroll
        for (int off = 8; off; off >>= 1) mt[r] = fmaxf(mt[r], __shfl_xor(mt[r], off));
      float al[4];
#pragma unroll
      for (int r = 0; r < 4; ++r) {
        float mn = fmaxf(m_r[r], mt[r]);
        al[r] = __expf(m_r[r] - mn);
        m_r[r] = mn;
      }
      float rs[4] = {0.f, 0.f, 0.f, 0.f};
#pragma unroll
      for (int ni = 0; ni < 4; ++ni)
#pragma unroll
        for (int r = 0; r < 4; ++r) {
          float p = __expf(sa[ni][r] - m_r[r]);
          rs[r] += p;
          int q = g * 4 + r, k = ni * 16 + lrow;
          Pl[w * 1024 + q * 64 + (k ^ ((q & 7) << 3))] = f2bf(p);
        }
#pragma unroll
      for (int r = 0; r < 4; ++r) {
#pragma unroll
        for (int off = 8; off; off >>= 1) rs[r] += __shfl_xor(rs[r], off);
        l_r[r] = l_r[r] * al[r] + rs[r];
      }
#pragma unroll
      for (int df = 0; df < 8; ++df)
#pragma unroll
        for (int r = 0; r < 4; ++r) ao[df][r] *= al[r];
      asm volatile("s_waitcnt lgkmcnt(0)" ::: "memory");
      __builtin_amdgcn_sched_barrier(0);
      s16x8 pa[2];
#pragma unroll
      for (int ks = 0; ks < 2; ++ks)
        pa[ks] = *(const s16x8*)&Pl[w * 1024 + lrow * 64 + ((ks * 32 + g * 8) ^ ((lrow & 7) << 3))];
#pragma unroll
      for (int df = 0; df < 8; ++df) {
#pragma unroll
        for (int ks = 0; ks < 2; ++ks) {
          int row = df * 16 + lrow;
          int cb = ks * 64 + g * 16;
          int scb = cb ^ ((row & 7) << 4);
          s16x8 vf = *(const s16x8*)&Vt[row * 64 + (scb >> 1)];
          ao[df] = MFMA(pa[ks], vf, ao[df], 0, 0, 0);
        }
      }
    }
#pragma unroll
    for (int df = 0; df < 8; ++df)
#pragma unroll
      for (int r = 0; r < 4; ++r) {
        int q = wq0 + g * 4 + r;
        float v = ao[df][r] / l_r[r];
        attn[((size_t)b * 2048 + q) * 2048 + h * 128 + df * 16 + lrow] = f2bf(v);
      }
    bar();
  }
}

// ---------------- modc ----------------
__global__ __launch_bounds__(256) void modc(const unsigned short* __restrict__ attnO,
                                            const unsigned short* __restrict__ h,
                                            const float* __restrict__ A,
                                            float* __restrict__ cvec) {
  const int D = 2048;
  int t = blockIdx.x * 4 + (threadIdx.x >> 6);
  int lane = threadIdx.x & 63;
  float aA[16] = {}, aH[16] = {};
  for (int i = 0; i < D / 64; ++i) {
    int d = i * 64 + lane;
    float av = bf2f(attnO[(size_t)t * D + d]);
    float hv = bf2f(h[(size_t)t * D + d]);
    const float* ar = A + (size_t)d * 16;
#pragma unroll
    for (int j = 0; j < 16; ++j) {
      float a = ar[j];
      aA[j] += av * a;
      aH[j] += hv * a;
    }
  }
#pragma unroll
  for (int j = 0; j < 16; ++j) {
#pragma unroll
    for (int off = 32; off; off >>= 1) {
      aA[j] += __shfl_xor(aA[j], off);
      aH[j] += __shfl_xor(aH[j], off);
    }
  }
#pragma unroll
  for (int j = 0; j < 16; ++j)
    if (lane == j) cvec[(size_t)t * 16 + j] = 0.1f * tanhf(aA[j]) * aH[j];
}

extern "C" void kernel_launch(void* const* d_in, const int* in_sizes, int n_in,
                              void* d_out, int out_size, void* d_ws, size_t ws_size,
                              hipStream_t stream) {
  const float* hs  = (const float*)d_in[0];
  const float* ln1 = (const float*)d_in[1];
  const float* ln2 = (const float*)d_in[2];
  const float* Wq  = (const float*)d_in[3];
  const float* Wk  = (const float*)d_in[4];
  const float* Wv  = (const float*)d_in[5];
  const float* Wo  = (const float*)d_in[6];
  const float* Am  = (const float*)d_in[7];
  const float* Bm  = (const float*)d_in[8];
  const float* Win = (const float*)d_in[9];
  const float* Wup = (const float*)d_in[10];
  const float* Wdn = (const float*)d_in[11];
  float* out = (float*)d_out;
  (void)in_sizes; (void)n_in;

  const int T = 4096;
  const int Dm = 2048, F = 8192;
  const size_t MB = (size_t)1 << 20;

  const size_t need = 184 * MB;
  if (ws_size < need) {
    hipMemsetAsync(d_out, 0, (size_t)out_size * 4, stream);
    return;
  }
  char* base = (char*)d_ws;
  unsigned short* tb    = (unsigned short*)(base);
  unsigned short* wqkv  = (unsigned short*)(base);
  unsigned short* vT    = (unsigned short*)(base);
  unsigned short* xb    = (unsigned short*)(base + 24 * MB);
  unsigned short* attnO = (unsigned short*)(base + 40 * MB);
  unsigned short* qkv   = (unsigned short*)(base + 64 * MB);
  unsigned short* win   = (unsigned short*)(base + 64 * MB);
  unsigned short* wo    = (unsigned short*)(base + 112 * MB);
  unsigned short* hb    = (unsigned short*)(base + 120 * MB);
  unsigned short* attn  = (unsigned short*)(base + 136 * MB);
  float*          cv    = (float*)(base + 136 * MB);
  unsigned short* wup   = (unsigned short*)(base + 152 * MB);
  unsigned short* wdn   = (unsigned short*)(base + 152 * MB);

  cvt_f32_bf16<<<2048, 256, 0, stream>>>(Wq, wqkv, Dm * Dm / 4);
  cvt_f32_bf16<<<2048, 256, 0, stream>>>(Wk, wqkv + (size_t)Dm * Dm, Dm * Dm / 4);
  cvt_f32_bf16<<<2048, 256, 0, stream>>>(Wv, wqkv + (size_t)2 * Dm * Dm, Dm * Dm / 4);
  cvt_f32_bf16<<<2048, 256, 0, stream>>>(Wo, wo, Dm * Dm / 4);
  rmsnorm_dual<<<T, 256, 0, stream>>>(hs, ln1, ln2, xb, hb);

  // QKV: BM=256 (MW=4), grid 16x48 = 768 = fully resident at 3 blocks/CU
  gemm_sb<E_NONE, 4><<<(T / 256) * (3 * Dm / 128), 512, 0, stream>>>(
      xb, wqkv, 3 * Dm, Dm, Dm / 64, qkv, nullptr, nullptr);

  vtrans<<<dim3(32, 2, 32), 256, 0, stream>>>(qkv, vT);
  attn_fwd2<<<dim3(16, 32), 256, 0, stream>>>(qkv, vT, attn);

  // O: BM=128 (MW=2), grid 32x16 = 512 = 2 blocks/CU resident
  gemm_sb<E_NONE, 2><<<(T / 128) * (Dm / 128), 256, 0, stream>>>(
      attn, wo, Dm, Dm, Dm / 64, attnO, nullptr, nullptr);

  modc<<<T / 4, 256, 0, stream>>>(attnO, hb, Am, cv);

  cvt_f32_bf16<<<2048, 256, 0, stream>>>(Win, win, F * Dm / 4);
  cvt_f32_bf16<<<2048, 256, 0, stream>>>(Wup, wup, F * Dm / 4);

  // fused gate/up: BM=256, grid 16x64 = 1024 = 2 exact rounds at 2 blocks/CU
  gemm_mlp_sb<<<(T / 256) * (F / 128), 512, 0, stream>>>(hb, win, wup, cv, Bm, tb);

  cvt_f32_bf16<<<2048, 256, 0, stream>>>(Wdn, wdn, Dm * F / 4);
  // down + residual: BM=128, grid 32x16 = 512, K=8192
  gemm_sb<E_RES, 2><<<(T / 128) * (Dm / 128), 256, 0, stream>>>(
      tb, wdn, Dm, F, F / 64, nullptr, out, hs);
}

// Round 10
// 965.669 us; speedup vs baseline: 6.4672x; 6.4672x over previous
//
#include <hip/hip_runtime.h>

#define DI __device__ __forceinline__

typedef short s16x8 __attribute__((ext_vector_type(8)));
typedef float f32x4 __attribute__((ext_vector_type(4)));

typedef __attribute__((address_space(1))) const unsigned int as1_cuint;
typedef __attribute__((address_space(3))) unsigned int as3_uint;

DI unsigned short f2bf(float f) {
  union { float f; unsigned int u; } v; v.f = f;
  unsigned int r = v.u + 0x7fffu + ((v.u >> 16) & 1u);
  return (unsigned short)(r >> 16);
}
DI float bf2f(unsigned short b) {
  union { unsigned int u; float f; } v; v.u = ((unsigned int)b) << 16;
  return v.f;
}

DI void gl_lds16(const void* g, void* l) {
  __builtin_amdgcn_global_load_lds((as1_cuint*)g, (as3_uint*)l, 16, 0, 0);
}

DI void bar() {
  __builtin_amdgcn_sched_barrier(0);
  __builtin_amdgcn_s_barrier();
  __builtin_amdgcn_sched_barrier(0);
}
DI void vm0() { asm volatile("s_waitcnt vmcnt(0)" ::: "memory"); }
DI void sfence() { __builtin_amdgcn_sched_barrier(0); }

#define MFMA __builtin_amdgcn_mfma_f32_16x16x32_bf16

// ---------------- fp32 -> bf16 convert ----------------
__global__ __launch_bounds__(256) void cvt_f32_bf16(const float* __restrict__ src,
                                                    unsigned short* __restrict__ dst, int n4) {
  int i = blockIdx.x * blockDim.x + threadIdx.x;
  int stride = gridDim.x * blockDim.x;
  for (; i < n4; i += stride) {
    float4 v = ((const float4*)src)[i];
    ((ushort4*)dst)[i] = make_ushort4(f2bf(v.x), f2bf(v.y), f2bf(v.z), f2bf(v.w));
  }
}

// ---------------- dual RMSNorm ----------------
__global__ __launch_bounds__(256) void rmsnorm_dual(const float* __restrict__ hs,
                                                    const float* __restrict__ w1,
                                                    const float* __restrict__ w2,
                                                    unsigned short* __restrict__ xo,
                                                    unsigned short* __restrict__ ho) {
  const int D = 2048;
  int t = blockIdx.x, tid = threadIdx.x;
  const float* row = hs + (size_t)t * D;
  float4 a = ((const float4*)row)[tid * 2];
  float4 b = ((const float4*)row)[tid * 2 + 1];
  float ss = a.x * a.x + a.y * a.y + a.z * a.z + a.w * a.w +
             b.x * b.x + b.y * b.y + b.z * b.z + b.w * b.w;
#pragma unroll
  for (int off = 32; off; off >>= 1) ss += __shfl_xor(ss, off);
  __shared__ float red[4];
  int wave = tid >> 6, lane = tid & 63;
  if (lane == 0) red[wave] = ss;
  __syncthreads();
  float tot = red[0] + red[1] + red[2] + red[3];
  float inv = rsqrtf(tot / (float)D + 1e-6f);
  int base = tid * 8;
  float vals[8] = {a.x, a.y, a.z, a.w, b.x, b.y, b.z, b.w};
  float4 w1a = ((const float4*)(w1 + base))[0];
  float4 w1b = ((const float4*)(w1 + base))[1];
  float4 w2a = ((const float4*)(w2 + base))[0];
  float4 w2b = ((const float4*)(w2 + base))[1];
  float w1v[8] = {w1a.x, w1a.y, w1a.z, w1a.w, w1b.x, w1b.y, w1b.z, w1b.w};
  float w2v[8] = {w2a.x, w2a.y, w2a.z, w2a.w, w2b.x, w2b.y, w2b.z, w2b.w};
  unsigned short ox[8], oh[8];
#pragma unroll
  for (int j = 0; j < 8; ++j) {
    float n = vals[j] * inv;
    ox[j] = f2bf(n * w1v[j]);
    oh[j] = f2bf(n * w2v[j]);
  }
  ushort4* xp = (ushort4*)(xo + (size_t)t * D + base);
  ushort4* hp = (ushort4*)(ho + (size_t)t * D + base);
  xp[0] = make_ushort4(ox[0], ox[1], ox[2], ox[3]);
  xp[1] = make_ushort4(ox[4], ox[5], ox[6], ox[7]);
  hp[0] = make_ushort4(oh[0], oh[1], oh[2], oh[3]);
  hp[1] = make_ushort4(oh[4], oh[5], oh[6], oh[7]);
}

// ======== 256x128 1-barrier/K-tile GEMM (R7 best): C = A @ Bt^T ========
#define E_NONE 0
#define E_RES 3

template <int EPI>
__global__ __launch_bounds__(512, 2) void gemm_n128(
    const unsigned short* __restrict__ Amat, const unsigned short* __restrict__ Bt,
    int N, int K, int NT,
    unsigned short* __restrict__ Cbf, float* __restrict__ Cf,
    const float* __restrict__ Res) {
  __shared__ __align__(16) unsigned short lds[49152];
  int tid = threadIdx.x, lane = tid & 63;
  int w = tid >> 6, wm = w >> 2, wn = w & 3;
  int lr = lane & 15, g = lane >> 4;
  int nbn = N >> 7, nwg = gridDim.x, wg = blockIdx.x;
  int cpx = nwg >> 3;
  int swz = (wg & 7) * cpx + (wg >> 3);
  int tm = swz / nbn, tn = swz - tm * nbn;
  size_t m0 = (size_t)tm * 256, n0 = (size_t)tn * 128;

  int boffA[4][2], boffB[2][2];
#pragma unroll
  for (int mi = 0; mi < 4; ++mi)
#pragma unroll
    for (int kh = 0; kh < 2; ++kh) {
      int row = mi * 32 + wm * 16 + lr;
      boffA[mi][kh] = row * 128 + ((kh * 64 + g * 16) ^ ((row & 7) << 4));
    }
#pragma unroll
  for (int ni = 0; ni < 2; ++ni)
#pragma unroll
    for (int kh = 0; kh < 2; ++kh) {
      int row = ni * 64 + wn * 16 + lr;
      boffB[ni][kh] = row * 128 + ((kh * 64 + g * 16) ^ ((row & 7) << 4));
    }
  const char* ldsb = (const char*)lds;

  int srow = tid >> 3;
  int scb = ((tid & 7) * 16) ^ ((srow & 7) << 4);
  const unsigned short* pA0 = Amat + (m0 + srow) * (size_t)K + (scb >> 1);
  const unsigned short* pA1 = pA0 + (size_t)128 * K;
  const unsigned short* pB  = Bt + (n0 + srow) * (size_t)K + (scb >> 1);
  const size_t jst = (size_t)64 * K;
  int dst = w * 512;

  f32x4 acc[8][2] = {};

  auto stg = [&](const unsigned short* p, int SLOT) {
    gl_lds16(p, &lds[SLOT * 8192 + dst]);
    gl_lds16(p + jst, &lds[SLOT * 8192 + 4096 + dst]);
  };
  auto stg_all = [&]() {
    stg(pA0, 0); stg(pA1, 1); stg(pB, 2);
    pA0 += 64; pA1 += 64; pB += 64;
  };

  for (int t = 0; t < NT; ++t) {
    bar();
    stg_all();
    vm0();
    bar();
    s16x8 afr[4][2], bfr[2][2];
#pragma unroll
    for (int mi = 0; mi < 4; ++mi)
#pragma unroll
      for (int kh = 0; kh < 2; ++kh)
        afr[mi][kh] = *(const s16x8*)(ldsb + 0 * 16384 + boffA[mi][kh]);
#pragma unroll
    for (int ni = 0; ni < 2; ++ni)
#pragma unroll
      for (int kh = 0; kh < 2; ++kh)
        bfr[ni][kh] = *(const s16x8*)(ldsb + 2 * 16384 + boffB[ni][kh]);
    __builtin_amdgcn_s_setprio(1);
#pragma unroll
    for (int mi = 0; mi < 4; ++mi)
#pragma unroll
      for (int ni = 0; ni < 2; ++ni)
#pragma unroll
        for (int kh = 0; kh < 2; ++kh)
          acc[mi][ni] = MFMA(afr[mi][kh], bfr[ni][kh], acc[mi][ni], 0, 0, 0);
    __builtin_amdgcn_s_setprio(0);
    s16x8 af1[4][2];
#pragma unroll
    for (int mi = 0; mi < 4; ++mi)
#pragma unroll
      for (int kh = 0; kh < 2; ++kh)
        af1[mi][kh] = *(const s16x8*)(ldsb + 1 * 16384 + boffA[mi][kh]);
    __builtin_amdgcn_s_setprio(1);
#pragma unroll
    for (int mi = 0; mi < 4; ++mi)
#pragma unroll
      for (int ni = 0; ni < 2; ++ni)
#pragma unroll
        for (int kh = 0; kh < 2; ++kh)
          acc[4 + mi][ni] = MFMA(af1[mi][kh], bfr[ni][kh], acc[4 + mi][ni], 0, 0, 0);
    __builtin_amdgcn_s_setprio(0);
  }

#pragma unroll
  for (int mh = 0; mh < 2; ++mh)
#pragma unroll
    for (int mi = 0; mi < 4; ++mi)
#pragma unroll
      for (int r = 0; r < 4; ++r) {
        size_t row = m0 + mh * 128 + mi * 32 + wm * 16 + g * 4 + r;
#pragma unroll
        for (int ni = 0; ni < 2; ++ni) {
          size_t col = n0 + ni * 64 + wn * 16 + lr;
          float v = acc[mh * 4 + mi][ni][r];
          if constexpr (EPI == E_RES) Cf[row * N + col] = Res[row * N + col] + v;
          else Cbf[row * N + col] = f2bf(v);
        }
      }
}

// ===== 128x128 fused MLP, 256 thr / 4 waves, single-buffer 48KB, 2 blocks/CU =====
// Out = silu(H@Wg^T + c@Bsm) * (H@Wu^T). Wave tile 128x32 per matrix (acc 128/thread).
// LDS: A [0,16K)B, Bg [16K,32K), Bu [32K,48K). Drift-overlap across co-resident blocks.
__global__ __launch_bounds__(256, 2) void gemm_mlp_db(
    const unsigned short* __restrict__ Hm, const unsigned short* __restrict__ Wg,
    const unsigned short* __restrict__ Wu,
    const float* __restrict__ cvec, const float* __restrict__ Bsm,
    unsigned short* __restrict__ Out) {
  const int N = 8192, K = 2048, NT = 32;
  __shared__ __align__(16) unsigned short lds[24576];
  int tid = threadIdx.x, lane = tid & 63;
  int w = tid >> 6;  // wave = N-group (4 x 32 cols)
  int lr = lane & 15, g = lane >> 4;
  int nbn = N >> 7, nwg = gridDim.x, wg = blockIdx.x;
  int cpx = nwg >> 3;
  int swz = (wg & 7) * cpx + (wg >> 3);
  int tm = swz / nbn, tn = swz - tm * nbn;
  size_t m0 = (size_t)tm * 128, n0 = (size_t)tn * 128;

  // hoisted frag byte offsets
  int boffA[8][2], boffBg[2][2], boffBu[2][2];
#pragma unroll
  for (int mi = 0; mi < 8; ++mi)
#pragma unroll
    for (int kh = 0; kh < 2; ++kh) {
      int row = mi * 16 + lr;
      boffA[mi][kh] = row * 128 + ((kh * 64 + g * 16) ^ ((row & 7) << 4));
    }
#pragma unroll
  for (int ni = 0; ni < 2; ++ni)
#pragma unroll
    for (int kh = 0; kh < 2; ++kh) {
      int row = w * 32 + ni * 16 + lr;
      int sz = row * 128 + ((kh * 64 + g * 16) ^ ((row & 7) << 4));
      boffBg[ni][kh] = 16384 + sz;
      boffBu[ni][kh] = 32768 + sz;
    }
  const char* ldsb = (const char*)lds;

  // staging: 3072 chunks of 16B, 12 per thread. i<4 -> A, i in [4,8) -> Bg, [8,12) -> Bu.
  const unsigned short* sp[12];
#pragma unroll
  for (int i = 0; i < 12; ++i) {
    int c = i * 256 + tid;
    const unsigned short* gb;
    size_t r0;
    int lrow;
    if (i < 4)      { gb = Hm; r0 = m0; lrow = c >> 3; }
    else if (i < 8) { gb = Wg; r0 = n0; lrow = (c - 1024) >> 3; }
    else            { gb = Wu; r0 = n0; lrow = (c - 2048) >> 3; }
    int cb = (c & 7) * 16;
    int scb = cb ^ ((lrow & 7) << 4);
    sp[i] = gb + (r0 + lrow) * (size_t)K + (scb >> 1);
  }

  f32x4 ag[8][2] = {}, au[8][2] = {};

  for (int t = 0; t < NT; ++t) {
    bar();
#pragma unroll
    for (int i = 0; i < 12; ++i) {
      gl_lds16(sp[i], &lds[i * 2048 + w * 512]);
      sp[i] += 64;
    }
    vm0();
    bar();
    s16x8 bg[2][2], bu[2][2];
#pragma unroll
    for (int ni = 0; ni < 2; ++ni)
#pragma unroll
      for (int kh = 0; kh < 2; ++kh) {
        bg[ni][kh] = *(const s16x8*)(ldsb + boffBg[ni][kh]);
        bu[ni][kh] = *(const s16x8*)(ldsb + boffBu[ni][kh]);
      }
    // A frags read per-mi inside the MFMA loop to cap VGPR pressure
    __builtin_amdgcn_s_setprio(1);
#pragma unroll
    for (int mi = 0; mi < 8; ++mi) {
      s16x8 a0 = *(const s16x8*)(ldsb + boffA[mi][0]);
      s16x8 a1 = *(const s16x8*)(ldsb + boffA[mi][1]);
#pragma unroll
      for (int ni = 0; ni < 2; ++ni) {
        ag[mi][ni] = MFMA(a0, bg[ni][0], ag[mi][ni], 0, 0, 0);
        ag[mi][ni] = MFMA(a1, bg[ni][1], ag[mi][ni], 0, 0, 0);
        au[mi][ni] = MFMA(a0, bu[ni][0], au[mi][ni], 0, 0, 0);
        au[mi][ni] = MFMA(a1, bu[ni][1], au[mi][ni], 0, 0, 0);
      }
    }
    __builtin_amdgcn_s_setprio(0);
  }

  // epilogue: c-tile 128x16 f32 (8KB @0) + Bsm 16x128 f32 (8KB @8192B)
  bar();
  float* cl = (float*)lds;
  float* bl = (float*)&lds[4096];  // elem offset 4096 = byte 8192
#pragma unroll
  for (int j = 0; j < 2; ++j) {
    int fi = tid * 2 + j;  // 0..511
    ((float4*)cl)[fi] = ((const float4*)(cvec + m0 * 16))[fi];
    ((float4*)bl)[fi] = *(const float4*)(Bsm + (size_t)(fi >> 5) * N + n0 + (fi & 31) * 4);
  }
  __syncthreads();

#pragma unroll
  for (int mi = 0; mi < 8; ++mi)
#pragma unroll
    for (int r = 0; r < 4; ++r) {
      int rr = mi * 16 + g * 4 + r;
      size_t row = m0 + rr;
#pragma unroll
      for (int ni = 0; ni < 2; ++ni) {
        int cc = w * 32 + ni * 16 + lr;
        size_t col = n0 + cc;
        float s = 0.f;
#pragma unroll
        for (int jj = 0; jj < 16; ++jj) s += cl[rr * 16 + jj] * bl[jj * 128 + cc];
        float gg = ag[mi][ni][r] + s;
        float sig = 1.f / (1.f + __expf(-gg));
        Out[row * N + col] = f2bf(gg * sig * au[mi][ni][r]);
      }
    }
}

// ---------- V transpose: vT[bh][d][k] ----------
__global__ __launch_bounds__(256) void vtrans(const unsigned short* __restrict__ qkv,
                                              unsigned short* __restrict__ vT) {
  __shared__ unsigned short t[64][72];
  int bh = blockIdx.z, b = bh >> 4, h = bh & 15;
  int k0 = blockIdx.x * 64, d0 = blockIdx.y * 64;
  int tid = threadIdx.x;
#pragma unroll
  for (int j = 0; j < 2; ++j) {
    int idx = tid + j * 256;
    int r = idx >> 3, c8 = (idx & 7) * 8;
    s16x8 v = *(const s16x8*)(qkv + ((size_t)(b * 2048 + k0 + r)) * 6144 + 4096 + h * 128 + d0 + c8);
#pragma unroll
    for (int e = 0; e < 8; ++e) t[r][c8 + e] = (unsigned short)v[e];
  }
  __syncthreads();
#pragma unroll
  for (int j = 0; j < 2; ++j) {
    int idx = tid + j * 256;
    int dr = idx >> 3, k8 = (idx & 7) * 8;
    s16x8 o;
#pragma unroll
    for (int e = 0; e < 8; ++e) o[e] = (short)t[k8 + e][dr];
    *(s16x8*)(vT + (size_t)bh * 262144 + (size_t)(d0 + dr) * 2048 + k0 + k8) = o;
  }
}

// ---------- causal flash attention: KVBLK=64, vT staging, balanced pair-pass ----------
__global__ __launch_bounds__(256, 2) void attn_fwd2(const unsigned short* __restrict__ qkv,
                                                    const unsigned short* __restrict__ vT,
                                                    unsigned short* __restrict__ attn) {
  const int LD = 6144;
  __shared__ __align__(16) unsigned short Kt[8192];
  __shared__ __align__(16) unsigned short Vt[8192];
  __shared__ __align__(16) unsigned short Pl[4096];
  int tid = threadIdx.x, w = tid >> 6, lane = tid & 63;
  int lrow = lane & 15, g = lane >> 4;
  int qp = blockIdx.x, bh = blockIdx.y, b = bh >> 4, h = bh & 15;
  const unsigned short* Qb = qkv + (size_t)b * 2048 * LD + h * 128;
  const unsigned short* Kb = Qb + 2048;
  const unsigned short* vTb = vT + (size_t)bh * 262144;
  const float scale = 0.08838834764831845f;

#pragma unroll
  for (int pass = 0; pass < 2; ++pass) {
    int qtile = pass ? (31 - qp) : qp;
    int wq0 = qtile * 64 + w * 16;
    s16x8 qf[4];
#pragma unroll
    for (int kc = 0; kc < 4; ++kc)
      qf[kc] = *(const s16x8*)(Qb + (size_t)(wq0 + lrow) * LD + kc * 32 + g * 8);
    f32x4 ao[8] = {};
    float m_r[4], l_r[4];
#pragma unroll
    for (int r = 0; r < 4; ++r) { m_r[r] = -1e30f; l_r[r] = 0.f; }
    int nkt = qtile + 1;

    for (int kt = 0; kt < nkt; ++kt) {
      int k0 = kt * 64;
      bar();
#pragma unroll
      for (int j = 0; j < 4; ++j) {
        int o = j * 4096 + tid * 16;
        int row = o >> 8, cb = o & 255;
        int scb = cb ^ ((row & 7) << 4);
        gl_lds16(Kb + (size_t)(k0 + row) * LD + (scb >> 1), &Kt[(j * 4096 + w * 1024) >> 1]);
      }
#pragma unroll
      for (int j = 0; j < 4; ++j) {
        int o = j * 4096 + tid * 16;
        int row = o >> 7, cb = o & 127;
        int scb = cb ^ ((row & 7) << 4);
        gl_lds16(vTb + (size_t)row * 2048 + k0 + (scb >> 1), &Vt[(j * 4096 + w * 1024) >> 1]);
      }
      vm0();
      bar();
      f32x4 sa[4] = {};
#pragma unroll
      for (int ni = 0; ni < 4; ++ni)
#pragma unroll
        for (int kc = 0; kc < 4; ++kc) {
          int row = ni * 16 + lrow;
          int cb = kc * 64 + g * 16;
          int scb = cb ^ ((row & 7) << 4);
          s16x8 kf = *(const s16x8*)&Kt[row * 128 + (scb >> 1)];
          sa[ni] = MFMA(qf[kc], kf, sa[ni], 0, 0, 0);
        }
      if (k0 + 63 > wq0) {
#pragma unroll
        for (int ni = 0; ni < 4; ++ni)
#pragma unroll
          for (int r = 0; r < 4; ++r) {
            int q_idx = wq0 + g * 4 + r, k_idx = k0 + ni * 16 + lrow;
            float sv = sa[ni][r] * scale;
            sa[ni][r] = (k_idx > q_idx) ? -1e30f : sv;
          }
      } else {
#pragma unroll
        for (int ni = 0; ni < 4; ++ni)
#pragma unroll
          for (int r = 0; r < 4; ++r) sa[ni][r] *= scale;
      }
      float mt[4];
#pragma unroll
      for (int r = 0; r < 4; ++r)
        mt[r] = fmaxf(fmaxf(sa[0][r], sa[1][r]), fmaxf(sa[2][r], sa[3][r]));
#pragma unroll
      for (int r = 0; r < 4; ++r)
#pragma unroll
        for (int off = 8; off; off >>= 1) mt[r] = fmaxf(mt[r], __shfl_xor(mt[r], off));
      float al[4];
#pragma unroll
      for (int r = 0; r < 4; ++r) {
        float mn = fmaxf(m_r[r], mt[r]);
        al[r] = __expf(m_r[r] - mn);
        m_r[r] = mn;
      }
      float rs[4] = {0.f, 0.f, 0.f, 0.f};
#pragma unroll
      for (int ni = 0; ni < 4; ++ni)
#pragma unroll
        for (int r = 0; r < 4; ++r) {
          float p = __expf(sa[ni][r] - m_r[r]);
          rs[r] += p;
          int q = g * 4 + r, k = ni * 16 + lrow;
          Pl[w * 1024 + q * 64 + (k ^ ((q & 7) << 3))] = f2bf(p);
        }
#pragma unroll
      for (int r = 0; r < 4; ++r) {
#pragma unroll
        for (int off = 8; off; off >>= 1) rs[r] += __shfl_xor(rs[r], off);
        l_r[r] = l_r[r] * al[r] + rs[r];
      }
#pragma unroll
      for (int df = 0; df < 8; ++df)
#pragma unroll
        for (int r = 0; r < 4; ++r) ao[df][r] *= al[r];
      asm volatile("s_waitcnt lgkmcnt(0)" ::: "memory");
      __builtin_amdgcn_sched_barrier(0);
      s16x8 pa[2];
#pragma unroll
      for (int ks = 0; ks < 2; ++ks)
        pa[ks] = *(const s16x8*)&Pl[w * 1024 + lrow * 64 + ((ks * 32 + g * 8) ^ ((lrow & 7) << 3))];
#pragma unroll
      for (int df = 0; df < 8; ++df) {
#pragma unroll
        for (int ks = 0; ks < 2; ++ks) {
          int row = df * 16 + lrow;
          int cb = ks * 64 + g * 16;
          int scb = cb ^ ((row & 7) << 4);
          s16x8 vf = *(const s16x8*)&Vt[row * 64 + (scb >> 1)];
          ao[df] = MFMA(pa[ks], vf, ao[df], 0, 0, 0);
        }
      }
    }
#pragma unroll
    for (int df = 0; df < 8; ++df)
#pragma unroll
      for (int r = 0; r < 4; ++r) {
        int q = wq0 + g * 4 + r;
        float v = ao[df][r] / l_r[r];
        attn[((size_t)b * 2048 + q) * 2048 + h * 128 + df * 16 + lrow] = f2bf(v);
      }
    bar();
  }
}

// ---------------- modc ----------------
__global__ __launch_bounds__(256) void modc(const unsigned short* __restrict__ attnO,
                                            const unsigned short* __restrict__ h,
                                            const float* __restrict__ A,
                                            float* __restrict__ cvec) {
  const int D = 2048;
  int t = blockIdx.x * 4 + (threadIdx.x >> 6);
  int lane = threadIdx.x & 63;
  float aA[16] = {}, aH[16] = {};
  for (int i = 0; i < D / 64; ++i) {
    int d = i * 64 + lane;
    float av = bf2f(attnO[(size_t)t * D + d]);
    float hv = bf2f(h[(size_t)t * D + d]);
    const float* ar = A + (size_t)d * 16;
#pragma unroll
    for (int j = 0; j < 16; ++j) {
      float a = ar[j];
      aA[j] += av * a;
      aH[j] += hv * a;
    }
  }
#pragma unroll
  for (int j = 0; j < 16; ++j) {
#pragma unroll
    for (int off = 32; off; off >>= 1) {
      aA[j] += __shfl_xor(aA[j], off);
      aH[j] += __shfl_xor(aH[j], off);
    }
  }
#pragma unroll
  for (int j = 0; j < 16; ++j)
    if (lane == j) cvec[(size_t)t * 16 + j] = 0.1f * tanhf(aA[j]) * aH[j];
}

extern "C" void kernel_launch(void* const* d_in, const int* in_sizes, int n_in,
                              void* d_out, int out_size, void* d_ws, size_t ws_size,
                              hipStream_t stream) {
  const float* hs  = (const float*)d_in[0];
  const float* ln1 = (const float*)d_in[1];
  const float* ln2 = (const float*)d_in[2];
  const float* Wq  = (const float*)d_in[3];
  const float* Wk  = (const float*)d_in[4];
  const float* Wv  = (const float*)d_in[5];
  const float* Wo  = (const float*)d_in[6];
  const float* Am  = (const float*)d_in[7];
  const float* Bm  = (const float*)d_in[8];
  const float* Win = (const float*)d_in[9];
  const float* Wup = (const float*)d_in[10];
  const float* Wdn = (const float*)d_in[11];
  float* out = (float*)d_out;
  (void)in_sizes; (void)n_in;

  const int T = 4096;
  const int Dm = 2048, F = 8192;
  const size_t MB = (size_t)1 << 20;

  const size_t need = 184 * MB;
  if (ws_size < need) {
    hipMemsetAsync(d_out, 0, (size_t)out_size * 4, stream);
    return;
  }
  char* base = (char*)d_ws;
  unsigned short* tb    = (unsigned short*)(base);
  unsigned short* wqkv  = (unsigned short*)(base);
  unsigned short* vT    = (unsigned short*)(base);
  unsigned short* xb    = (unsigned short*)(base + 24 * MB);
  unsigned short* attnO = (unsigned short*)(base + 40 * MB);
  unsigned short* qkv   = (unsigned short*)(base + 64 * MB);
  unsigned short* win   = (unsigned short*)(base + 64 * MB);
  unsigned short* wo    = (unsigned short*)(base + 112 * MB);
  unsigned short* hb    = (unsigned short*)(base + 120 * MB);
  unsigned short* attn  = (unsigned short*)(base + 136 * MB);
  float*          cv    = (float*)(base + 136 * MB);
  unsigned short* wup   = (unsigned short*)(base + 152 * MB);
  unsigned short* wdn   = (unsigned short*)(base + 152 * MB);

  cvt_f32_bf16<<<2048, 256, 0, stream>>>(Wq, wqkv, Dm * Dm / 4);
  cvt_f32_bf16<<<2048, 256, 0, stream>>>(Wk, wqkv + (size_t)Dm * Dm, Dm * Dm / 4);
  cvt_f32_bf16<<<2048, 256, 0, stream>>>(Wv, wqkv + (size_t)2 * Dm * Dm, Dm * Dm / 4);
  cvt_f32_bf16<<<2048, 256, 0, stream>>>(Wo, wo, Dm * Dm / 4);
  rmsnorm_dual<<<T, 256, 0, stream>>>(hs, ln1, ln2, xb, hb);

  // QKV projection: 16 x 48 = 768 blocks (3 exact rounds)
  gemm_n128<E_NONE><<<(T / 256) * (3 * Dm / 128), 512, 0, stream>>>(
      xb, wqkv, 3 * Dm, Dm, Dm / 64, qkv, nullptr, nullptr);

  vtrans<<<dim3(32, 2, 32), 256, 0, stream>>>(qkv, vT);
  attn_fwd2<<<dim3(16, 32), 256, 0, stream>>>(qkv, vT, attn);

  // O projection: 16 x 16 = 256 blocks (1 exact round)
  gemm_n128<E_NONE><<<(T / 256) * (Dm / 128), 512, 0, stream>>>(
      attn, wo, Dm, Dm, Dm / 64, attnO, nullptr, nullptr);

  modc<<<T / 4, 256, 0, stream>>>(attnO, hb, Am, cv);

  cvt_f32_bf16<<<2048, 256, 0, stream>>>(Win, win, F * Dm / 4);
  cvt_f32_bf16<<<2048, 256, 0, stream>>>(Wup, wup, F * Dm / 4);

  // fused gate/up: 32 x 64 = 2048 blocks of 256 thr (4 exact rounds at 2 blocks/CU)
  gemm_mlp_db<<<(T / 128) * (F / 128), 256, 0, stream>>>(hb, win, wup, cv, Bm, tb);

  cvt_f32_bf16<<<2048, 256, 0, stream>>>(Wdn, wdn, Dm * F / 4);
  // down + residual: 16 x 16 = 256 blocks (1 exact round), K=8192
  gemm_n128<E_RES><<<(T / 256) * (Dm / 128), 512, 0, stream>>>(
      tb, wdn, Dm, F, F / 64, nullptr, out, hs);
}

// Round 11
// 894.820 us; speedup vs baseline: 6.9793x; 1.0792x over previous
//
#include <hip/hip_runtime.h>

#define DI __device__ __forceinline__

typedef short s16x8 __attribute__((ext_vector_type(8)));
typedef float f32x4 __attribute__((ext_vector_type(4)));

typedef __attribute__((address_space(1))) const unsigned int as1_cuint;
typedef __attribute__((address_space(3))) unsigned int as3_uint;

DI unsigned short f2bf(float f) {
  union { float f; unsigned int u; } v; v.f = f;
  unsigned int r = v.u + 0x7fffu + ((v.u >> 16) & 1u);
  return (unsigned short)(r >> 16);
}
DI float bf2f(unsigned short b) {
  union { unsigned int u; float f; } v; v.u = ((unsigned int)b) << 16;
  return v.f;
}

DI void gl_lds16(const void* g, void* l) {
  __builtin_amdgcn_global_load_lds((as1_cuint*)g, (as3_uint*)l, 16, 0, 0);
}

DI void bar() {
  __builtin_amdgcn_sched_barrier(0);
  __builtin_amdgcn_s_barrier();
  __builtin_amdgcn_sched_barrier(0);
}
DI void vm0() { asm volatile("s_waitcnt vmcnt(0)" ::: "memory"); }
DI void vm6() { asm volatile("s_waitcnt vmcnt(6)" ::: "memory"); }
DI void sfence() { __builtin_amdgcn_sched_barrier(0); }

#define MFMA __builtin_amdgcn_mfma_f32_16x16x32_bf16

// stage one 128x64 bf16 half-tile (16 KiB) linearly into LDS; XOR-swizzle applied on
// the GLOBAL source (rule #21). 512 threads, 2 gl_lds16 per thread.
DI void stage_half(const unsigned short* gb, size_t r0, int K, int kt,
                   unsigned short* lh, int tid) {
#pragma unroll
  for (int j = 0; j < 2; ++j) {
    int o = j * 8192 + tid * 16;  // byte offset in half-tile
    int row = o >> 7, cb = o & 127;
    int scb = cb ^ ((row & 7) << 4);
    gl_lds16(gb + (r0 + row) * (size_t)K + kt + (scb >> 1),
             lh + ((j * 8192 + (tid >> 6) * 1024) >> 1));
  }
}

// read one MFMA fragment (16B/lane) from a swizzled half-tile (64-elem rows)
DI s16x8 rd_frag(const unsigned short* lds, int baseE, int rwh, int kh, int lane) {
  int cb = kh * 64 + ((lane >> 4) << 4);
  int scb = cb ^ ((rwh & 7) << 4);
  return *(const s16x8*)&lds[baseE + rwh * 64 + (scb >> 1)];
}

// ---------------- fp32 -> bf16 convert ----------------
__global__ __launch_bounds__(256) void cvt_f32_bf16(const float* __restrict__ src,
                                                    unsigned short* __restrict__ dst, int n4) {
  int i = blockIdx.x * blockDim.x + threadIdx.x;
  int stride = gridDim.x * blockDim.x;
  for (; i < n4; i += stride) {
    float4 v = ((const float4*)src)[i];
    ((ushort4*)dst)[i] = make_ushort4(f2bf(v.x), f2bf(v.y), f2bf(v.z), f2bf(v.w));
  }
}

// ---------------- dual RMSNorm ----------------
__global__ __launch_bounds__(256) void rmsnorm_dual(const float* __restrict__ hs,
                                                    const float* __restrict__ w1,
                                                    const float* __restrict__ w2,
                                                    unsigned short* __restrict__ xo,
                                                    unsigned short* __restrict__ ho) {
  const int D = 2048;
  int t = blockIdx.x, tid = threadIdx.x;
  const float* row = hs + (size_t)t * D;
  float4 a = ((const float4*)row)[tid * 2];
  float4 b = ((const float4*)row)[tid * 2 + 1];
  float ss = a.x * a.x + a.y * a.y + a.z * a.z + a.w * a.w +
             b.x * b.x + b.y * b.y + b.z * b.z + b.w * b.w;
#pragma unroll
  for (int off = 32; off; off >>= 1) ss += __shfl_xor(ss, off);
  __shared__ float red[4];
  int wave = tid >> 6, lane = tid & 63;
  if (lane == 0) red[wave] = ss;
  __syncthreads();
  float tot = red[0] + red[1] + red[2] + red[3];
  float inv = rsqrtf(tot / (float)D + 1e-6f);
  int base = tid * 8;
  float vals[8] = {a.x, a.y, a.z, a.w, b.x, b.y, b.z, b.w};
  float4 w1a = ((const float4*)(w1 + base))[0];
  float4 w1b = ((const float4*)(w1 + base))[1];
  float4 w2a = ((const float4*)(w2 + base))[0];
  float4 w2b = ((const float4*)(w2 + base))[1];
  float w1v[8] = {w1a.x, w1a.y, w1a.z, w1a.w, w1b.x, w1b.y, w1b.z, w1b.w};
  float w2v[8] = {w2a.x, w2a.y, w2a.z, w2a.w, w2b.x, w2b.y, w2b.z, w2b.w};
  unsigned short ox[8], oh[8];
#pragma unroll
  for (int j = 0; j < 8; ++j) {
    float n = vals[j] * inv;
    ox[j] = f2bf(n * w1v[j]);
    oh[j] = f2bf(n * w2v[j]);
  }
  ushort4* xp = (ushort4*)(xo + (size_t)t * D + base);
  ushort4* hp = (ushort4*)(ho + (size_t)t * D + base);
  xp[0] = make_ushort4(ox[0], ox[1], ox[2], ox[3]);
  xp[1] = make_ushort4(ox[4], ox[5], ox[6], ox[7]);
  hp[0] = make_ushort4(oh[0], oh[1], oh[2], oh[3]);
  hp[1] = make_ushort4(oh[4], oh[5], oh[6], oh[7]);
}

// ======== 256x128 1-barrier/K-tile GEMM (R7 best): C = A @ Bt^T ========
#define E_NONE 0
#define E_RES 3

template <int EPI>
__global__ __launch_bounds__(512, 2) void gemm_n128(
    const unsigned short* __restrict__ Amat, const unsigned short* __restrict__ Bt,
    int N, int K, int NT,
    unsigned short* __restrict__ Cbf, float* __restrict__ Cf,
    const float* __restrict__ Res) {
  __shared__ __align__(16) unsigned short lds[49152];
  int tid = threadIdx.x, lane = tid & 63;
  int w = tid >> 6, wm = w >> 2, wn = w & 3;
  int lr = lane & 15, g = lane >> 4;
  int nbn = N >> 7, nwg = gridDim.x, wg = blockIdx.x;
  int cpx = nwg >> 3;
  int swz = (wg & 7) * cpx + (wg >> 3);
  int tm = swz / nbn, tn = swz - tm * nbn;
  size_t m0 = (size_t)tm * 256, n0 = (size_t)tn * 128;

  int boffA[4][2], boffB[2][2];
#pragma unroll
  for (int mi = 0; mi < 4; ++mi)
#pragma unroll
    for (int kh = 0; kh < 2; ++kh) {
      int row = mi * 32 + wm * 16 + lr;
      boffA[mi][kh] = row * 128 + ((kh * 64 + g * 16) ^ ((row & 7) << 4));
    }
#pragma unroll
  for (int ni = 0; ni < 2; ++ni)
#pragma unroll
    for (int kh = 0; kh < 2; ++kh) {
      int row = ni * 64 + wn * 16 + lr;
      boffB[ni][kh] = row * 128 + ((kh * 64 + g * 16) ^ ((row & 7) << 4));
    }
  const char* ldsb = (const char*)lds;

  int srow = tid >> 3;
  int scb = ((tid & 7) * 16) ^ ((srow & 7) << 4);
  const unsigned short* pA0 = Amat + (m0 + srow) * (size_t)K + (scb >> 1);
  const unsigned short* pA1 = pA0 + (size_t)128 * K;
  const unsigned short* pB  = Bt + (n0 + srow) * (size_t)K + (scb >> 1);
  const size_t jst = (size_t)64 * K;
  int dst = w * 512;

  f32x4 acc[8][2] = {};

  auto stg = [&](const unsigned short* p, int SLOT) {
    gl_lds16(p, &lds[SLOT * 8192 + dst]);
    gl_lds16(p + jst, &lds[SLOT * 8192 + 4096 + dst]);
  };
  auto stg_all = [&]() {
    stg(pA0, 0); stg(pA1, 1); stg(pB, 2);
    pA0 += 64; pA1 += 64; pB += 64;
  };

  for (int t = 0; t < NT; ++t) {
    bar();
    stg_all();
    vm0();
    bar();
    s16x8 afr[4][2], bfr[2][2];
#pragma unroll
    for (int mi = 0; mi < 4; ++mi)
#pragma unroll
      for (int kh = 0; kh < 2; ++kh)
        afr[mi][kh] = *(const s16x8*)(ldsb + 0 * 16384 + boffA[mi][kh]);
#pragma unroll
    for (int ni = 0; ni < 2; ++ni)
#pragma unroll
      for (int kh = 0; kh < 2; ++kh)
        bfr[ni][kh] = *(const s16x8*)(ldsb + 2 * 16384 + boffB[ni][kh]);
    __builtin_amdgcn_s_setprio(1);
#pragma unroll
    for (int mi = 0; mi < 4; ++mi)
#pragma unroll
      for (int ni = 0; ni < 2; ++ni)
#pragma unroll
        for (int kh = 0; kh < 2; ++kh)
          acc[mi][ni] = MFMA(afr[mi][kh], bfr[ni][kh], acc[mi][ni], 0, 0, 0);
    __builtin_amdgcn_s_setprio(0);
    s16x8 af1[4][2];
#pragma unroll
    for (int mi = 0; mi < 4; ++mi)
#pragma unroll
      for (int kh = 0; kh < 2; ++kh)
        af1[mi][kh] = *(const s16x8*)(ldsb + 1 * 16384 + boffA[mi][kh]);
    __builtin_amdgcn_s_setprio(1);
#pragma unroll
    for (int mi = 0; mi < 4; ++mi)
#pragma unroll
      for (int ni = 0; ni < 2; ++ni)
#pragma unroll
        for (int kh = 0; kh < 2; ++kh)
          acc[4 + mi][ni] = MFMA(af1[mi][kh], bfr[ni][kh], acc[4 + mi][ni], 0, 0, 0);
    __builtin_amdgcn_s_setprio(0);
  }

#pragma unroll
  for (int mh = 0; mh < 2; ++mh)
#pragma unroll
    for (int mi = 0; mi < 4; ++mi)
#pragma unroll
      for (int r = 0; r < 4; ++r) {
        size_t row = m0 + mh * 128 + mi * 32 + wm * 16 + g * 4 + r;
#pragma unroll
        for (int ni = 0; ni < 2; ++ni) {
          size_t col = n0 + ni * 64 + wn * 16 + lr;
          float v = acc[mh * 4 + mi][ni][r];
          if constexpr (EPI == E_RES) Cf[row * N + col] = Res[row * N + col] + v;
          else Cbf[row * N + col] = f2bf(v);
        }
      }
}

// ===== concat-B 256^2 8-phase fused MLP (m201 template, R3-verified schedule) =====
// C-tile 256 x [gate 128 | up 128]: slot2 = Wg rows n0.., slot3 = Wu rows n0...
// acc[mh*4+mi][nh*2+ni]: nh=0 -> gate, nh=1 -> up at IDENTICAL (row, col) -> lane-local fusion.
// LDS 128KB: [2 buf][4 half-tiles][8192 elems]; stage 1 half-tile/phase; vmcnt6 at p3.
__global__ __launch_bounds__(512, 2) void gemm_mlp256(
    const unsigned short* __restrict__ Hm, const unsigned short* __restrict__ Wg,
    const unsigned short* __restrict__ Wu,
    const float* __restrict__ cvec, const float* __restrict__ Bsm,
    unsigned short* __restrict__ Out) {
  const int N = 8192, K = 2048, NT = 32;
  __shared__ __align__(16) unsigned short lds[65536];
  int tid = threadIdx.x, lane = tid & 63;
  int w = tid >> 6, wm = w >> 2, wn = w & 3;
  int lr = lane & 15, lkh = lane >> 4;
  int nbn = 64;  // F/128
  int nwg = gridDim.x, wg = blockIdx.x;
  int cpx = nwg >> 3;
  int swz = (wg & 7) * cpx + (wg >> 3);
  int tm = swz / nbn, tn = swz - tm * nbn;
  size_t m0 = (size_t)tm * 256, n0 = (size_t)tn * 128;

  auto stage = [&](int tau, int slot) {  // 0=A0 1=A1 2=Wg 3=Wu
    if (tau >= NT) return;
    const unsigned short* gb = (slot == 2) ? Wg : (slot == 3) ? Wu : Hm;
    size_t r0 = (slot >= 2) ? n0 : (m0 + (size_t)slot * 128);
    stage_half(gb, r0, K, tau * 64, &lds[(tau & 1) * 32768 + slot * 8192], tid);
  };

  // prologue: tile0 {A0,B0,A1,B1}, tile1 {A0,B0,A1}; 3 half-tiles stay in flight
  stage(0, 0); stage(0, 2); stage(0, 1); stage(0, 3);
  stage(1, 0); stage(1, 2); stage(1, 1);
  vm6();
  bar();

  f32x4 acc[8][4] = {};  // [mh*4+mi][nh*2+ni]
  s16x8 afr[4][2], bfr[2][2][2];

  for (int t = 0; t < NT; ++t) {
    int buf = (t & 1) * 32768;
    // p0: read A0(8) + B0(4); stage B1(t+1)
#pragma unroll
    for (int mi = 0; mi < 4; ++mi)
#pragma unroll
      for (int kh = 0; kh < 2; ++kh)
        afr[mi][kh] = rd_frag(lds, buf + 0 * 8192, mi * 32 + wm * 16 + lr, kh, lane);
#pragma unroll
    for (int ni = 0; ni < 2; ++ni)
#pragma unroll
      for (int kh = 0; kh < 2; ++kh)
        bfr[0][ni][kh] = rd_frag(lds, buf + 2 * 8192, ni * 64 + wn * 16 + lr, kh, lane);
    stage(t + 1, 3);
    bar();
    __builtin_amdgcn_s_setprio(1);
#pragma unroll
    for (int mi = 0; mi < 4; ++mi)
#pragma unroll
      for (int ni = 0; ni < 2; ++ni)
#pragma unroll
        for (int kh = 0; kh < 2; ++kh)
          acc[mi][ni] = MFMA(afr[mi][kh], bfr[0][ni][kh], acc[mi][ni], 0, 0, 0);
    __builtin_amdgcn_s_setprio(0);
    bar();
    // p1: read B1(4); stage A0(t+2)
#pragma unroll
    for (int ni = 0; ni < 2; ++ni)
#pragma unroll
      for (int kh = 0; kh < 2; ++kh)
        bfr[1][ni][kh] = rd_frag(lds, buf + 3 * 8192, ni * 64 + wn * 16 + lr, kh, lane);
    stage(t + 2, 0);
    bar();
    __builtin_amdgcn_s_setprio(1);
#pragma unroll
    for (int mi = 0; mi < 4; ++mi)
#pragma unroll
      for (int ni = 0; ni < 2; ++ni)
#pragma unroll
        for (int kh = 0; kh < 2; ++kh)
          acc[mi][2 + ni] = MFMA(afr[mi][kh], bfr[1][ni][kh], acc[mi][2 + ni], 0, 0, 0);
    __builtin_amdgcn_s_setprio(0);
    bar();
    // p2: read A1(8); stage B0(t+2)
#pragma unroll
    for (int mi = 0; mi < 4; ++mi)
#pragma unroll
      for (int kh = 0; kh < 2; ++kh)
        afr[mi][kh] = rd_frag(lds, buf + 1 * 8192, mi * 32 + wm * 16 + lr, kh, lane);
    stage(t + 2, 2);
    bar();
    __builtin_amdgcn_s_setprio(1);
#pragma unroll
    for (int mi = 0; mi < 4; ++mi)
#pragma unroll
      for (int ni = 0; ni < 2; ++ni)
#pragma unroll
        for (int kh = 0; kh < 2; ++kh)
          acc[4 + mi][ni] = MFMA(afr[mi][kh], bfr[0][ni][kh], acc[4 + mi][ni], 0, 0, 0);
    __builtin_amdgcn_s_setprio(0);
    bar();
    // p3: stage A1(t+2); boundary vmcnt
    stage(t + 2, 1);
    bar();
    __builtin_amdgcn_s_setprio(1);
#pragma unroll
    for (int mi = 0; mi < 4; ++mi)
#pragma unroll
      for (int ni = 0; ni < 2; ++ni)
#pragma unroll
        for (int kh = 0; kh < 2; ++kh)
          acc[4 + mi][2 + ni] = MFMA(afr[mi][kh], bfr[1][ni][kh], acc[4 + mi][2 + ni], 0, 0, 0);
    __builtin_amdgcn_s_setprio(0);
    if (t < NT - 2) vm6();
    else if (t == NT - 2) vm0();
    bar();
  }

  // epilogue: c-tile 256x16 f32 (16KB @0) + Bsm 16x128 f32 (8KB @byte 32768)
  float* cl = (float*)lds;
  float* bl = (float*)&lds[16384];
#pragma unroll
  for (int j = 0; j < 2; ++j) {
    int fi = tid * 2 + j;  // 0..1023
    ((float4*)cl)[fi] = ((const float4*)(cvec + m0 * 16))[fi];
  }
  {
    int fi = tid;  // 0..511
    ((float4*)bl)[fi] = *(const float4*)(Bsm + (size_t)(fi >> 5) * N + n0 + (fi & 31) * 4);
  }
  bar();

#pragma unroll
  for (int mh = 0; mh < 2; ++mh)
#pragma unroll
    for (int mi = 0; mi < 4; ++mi)
#pragma unroll
      for (int r = 0; r < 4; ++r) {
        int rr = mh * 128 + mi * 32 + wm * 16 + lkh * 4 + r;
        size_t row = m0 + rr;
#pragma unroll
        for (int ni = 0; ni < 2; ++ni) {
          int coff = ni * 64 + wn * 16 + lr;
          size_t col = n0 + coff;
          float s = 0.f;
#pragma unroll
          for (int jj = 0; jj < 16; ++jj) s += cl[rr * 16 + jj] * bl[jj * 128 + coff];
          float gg = acc[mh * 4 + mi][ni][r] + s;         // gate
          float uu = acc[mh * 4 + mi][2 + ni][r];          // up (same row,col)
          float sig = 1.f / (1.f + __expf(-gg));
          Out[row * N + col] = f2bf(gg * sig * uu);
        }
      }
}

// ---------- V transpose: vT[bh][d][k] ----------
__global__ __launch_bounds__(256) void vtrans(const unsigned short* __restrict__ qkv,
                                              unsigned short* __restrict__ vT) {
  __shared__ unsigned short t[64][72];
  int bh = blockIdx.z, b = bh >> 4, h = bh & 15;
  int k0 = blockIdx.x * 64, d0 = blockIdx.y * 64;
  int tid = threadIdx.x;
#pragma unroll
  for (int j = 0; j < 2; ++j) {
    int idx = tid + j * 256;
    int r = idx >> 3, c8 = (idx & 7) * 8;
    s16x8 v = *(const s16x8*)(qkv + ((size_t)(b * 2048 + k0 + r)) * 6144 + 4096 + h * 128 + d0 + c8);
#pragma unroll
    for (int e = 0; e < 8; ++e) t[r][c8 + e] = (unsigned short)v[e];
  }
  __syncthreads();
#pragma unroll
  for (int j = 0; j < 2; ++j) {
    int idx = tid + j * 256;
    int dr = idx >> 3, k8 = (idx & 7) * 8;
    s16x8 o;
#pragma unroll
    for (int e = 0; e < 8; ++e) o[e] = (short)t[k8 + e][dr];
    *(s16x8*)(vT + (size_t)bh * 262144 + (size_t)(d0 + dr) * 2048 + k0 + k8) = o;
  }
}

// ---------- causal flash attention: KVBLK=64, vT staging, balanced pair-pass ----------
__global__ __launch_bounds__(256, 2) void attn_fwd2(const unsigned short* __restrict__ qkv,
                                                    const unsigned short* __restrict__ vT,
                                                    unsigned short* __restrict__ attn) {
  const int LD = 6144;
  __shared__ __align__(16) unsigned short Kt[8192];
  __shared__ __align__(16) unsigned short Vt[8192];
  __shared__ __align__(16) unsigned short Pl[4096];
  int tid = threadIdx.x, w = tid >> 6, lane = tid & 63;
  int lrow = lane & 15, g = lane >> 4;
  int qp = blockIdx.x, bh = blockIdx.y, b = bh >> 4, h = bh & 15;
  const unsigned short* Qb = qkv + (size_t)b * 2048 * LD + h * 128;
  const unsigned short* Kb = Qb + 2048;
  const unsigned short* vTb = vT + (size_t)bh * 262144;
  const float scale = 0.08838834764831845f;

#pragma unroll
  for (int pass = 0; pass < 2; ++pass) {
    int qtile = pass ? (31 - qp) : qp;
    int wq0 = qtile * 64 + w * 16;
    s16x8 qf[4];
#pragma unroll
    for (int kc = 0; kc < 4; ++kc)
      qf[kc] = *(const s16x8*)(Qb + (size_t)(wq0 + lrow) * LD + kc * 32 + g * 8);
    f32x4 ao[8] = {};
    float m_r[4], l_r[4];
#pragma unroll
    for (int r = 0; r < 4; ++r) { m_r[r] = -1e30f; l_r[r] = 0.f; }
    int nkt = qtile + 1;

    for (int kt = 0; kt < nkt; ++kt) {
      int k0 = kt * 64;
      bar();
#pragma unroll
      for (int j = 0; j < 4; ++j) {
        int o = j * 4096 + tid * 16;
        int row = o >> 8, cb = o & 255;
        int scb = cb ^ ((row & 7) << 4);
        gl_lds16(Kb + (size_t)(k0 + row) * LD + (scb >> 1), &Kt[(j * 4096 + w * 1024) >> 1]);
      }
#pragma unroll
      for (int j = 0; j < 4; ++j) {
        int o = j * 4096 + tid * 16;
        int row = o >> 7, cb = o & 127;
        int scb = cb ^ ((row & 7) << 4);
        gl_lds16(vTb + (size_t)row * 2048 + k0 + (scb >> 1), &Vt[(j * 4096 + w * 1024) >> 1]);
      }
      vm0();
      bar();
      f32x4 sa[4] = {};
#pragma unroll
      for (int ni = 0; ni < 4; ++ni)
#pragma unroll
        for (int kc = 0; kc < 4; ++kc) {
          int row = ni * 16 + lrow;
          int cb = kc * 64 + g * 16;
          int scb = cb ^ ((row & 7) << 4);
          s16x8 kf = *(const s16x8*)&Kt[row * 128 + (scb >> 1)];
          sa[ni] = MFMA(qf[kc], kf, sa[ni], 0, 0, 0);
        }
      if (k0 + 63 > wq0) {
#pragma unroll
        for (int ni = 0; ni < 4; ++ni)
#pragma unroll
          for (int r = 0; r < 4; ++r) {
            int q_idx = wq0 + g * 4 + r, k_idx = k0 + ni * 16 + lrow;
            float sv = sa[ni][r] * scale;
            sa[ni][r] = (k_idx > q_idx) ? -1e30f : sv;
          }
      } else {
#pragma unroll
        for (int ni = 0; ni < 4; ++ni)
#pragma unroll
          for (int r = 0; r < 4; ++r) sa[ni][r] *= scale;
      }
      float mt[4];
#pragma unroll
      for (int r = 0; r < 4; ++r)
        mt[r] = fmaxf(fmaxf(sa[0][r], sa[1][r]), fmaxf(sa[2][r], sa[3][r]));
#pragma unroll
      for (int r = 0; r < 4; ++r)
#pragma unroll
        for (int off = 8; off; off >>= 1) mt[r] = fmaxf(mt[r], __shfl_xor(mt[r], off));
      float al[4];
#pragma unroll
      for (int r = 0; r < 4; ++r) {
        float mn = fmaxf(m_r[r], mt[r]);
        al[r] = __expf(m_r[r] - mn);
        m_r[r] = mn;
      }
      float rs[4] = {0.f, 0.f, 0.f, 0.f};
#pragma unroll
      for (int ni = 0; ni < 4; ++ni)
#pragma unroll
        for (int r = 0; r < 4; ++r) {
          float p = __expf(sa[ni][r] - m_r[r]);
          rs[r] += p;
          int q = g * 4 + r, k = ni * 16 + lrow;
          Pl[w * 1024 + q * 64 + (k ^ ((q & 7) << 3))] = f2bf(p);
        }
#pragma unroll
      for (int r = 0; r < 4; ++r) {
#pragma unroll
        for (int off = 8; off; off >>= 1) rs[r] += __shfl_xor(rs[r], off);
        l_r[r] = l_r[r] * al[r] + rs[r];
      }
#pragma unroll
      for (int df = 0; df < 8; ++df)
#pragma unroll
        for (int r = 0; r < 4; ++r) ao[df][r] *= al[r];
      asm volatile("s_waitcnt lgkmcnt(0)" ::: "memory");
      __builtin_amdgcn_sched_barrier(0);
      s16x8 pa[2];
#pragma unroll
      for (int ks = 0; ks < 2; ++ks)
        pa[ks] = *(const s16x8*)&Pl[w * 1024 + lrow * 64 + ((ks * 32 + g * 8) ^ ((lrow & 7) << 3))];
#pragma unroll
      for (int df = 0; df < 8; ++df) {
#pragma unroll
        for (int ks = 0; ks < 2; ++ks) {
          int row = df * 16 + lrow;
          int cb = ks * 64 + g * 16;
          int scb = cb ^ ((row & 7) << 4);
          s16x8 vf = *(const s16x8*)&Vt[row * 64 + (scb >> 1)];
          ao[df] = MFMA(pa[ks], vf, ao[df], 0, 0, 0);
        }
      }
    }
#pragma unroll
    for (int df = 0; df < 8; ++df)
#pragma unroll
      for (int r = 0; r < 4; ++r) {
        int q = wq0 + g * 4 + r;
        float v = ao[df][r] / l_r[r];
        attn[((size_t)b * 2048 + q) * 2048 + h * 128 + df * 16 + lrow] = f2bf(v);
      }
    bar();
  }
}

// ---------------- modc ----------------
__global__ __launch_bounds__(256) void modc(const unsigned short* __restrict__ attnO,
                                            const unsigned short* __restrict__ h,
                                            const float* __restrict__ A,
                                            float* __restrict__ cvec) {
  const int D = 2048;
  int t = blockIdx.x * 4 + (threadIdx.x >> 6);
  int lane = threadIdx.x & 63;
  float aA[16] = {}, aH[16] = {};
  for (int i = 0; i < D / 64; ++i) {
    int d = i * 64 + lane;
    float av = bf2f(attnO[(size_t)t * D + d]);
    float hv = bf2f(h[(size_t)t * D + d]);
    const float* ar = A + (size_t)d * 16;
#pragma unroll
    for (int j = 0; j < 16; ++j) {
      float a = ar[j];
      aA[j] += av * a;
      aH[j] += hv * a;
    }
  }
#pragma unroll
  for (int j = 0; j < 16; ++j) {
#pragma unroll
    for (int off = 32; off; off >>= 1) {
      aA[j] += __shfl_xor(aA[j], off);
      aH[j] += __shfl_xor(aH[j], off);
    }
  }
#pragma unroll
  for (int j = 0; j < 16; ++j)
    if (lane == j) cvec[(size_t)t * 16 + j] = 0.1f * tanhf(aA[j]) * aH[j];
}

extern "C" void kernel_launch(void* const* d_in, const int* in_sizes, int n_in,
                              void* d_out, int out_size, void* d_ws, size_t ws_size,
                              hipStream_t stream) {
  const float* hs  = (const float*)d_in[0];
  const float* ln1 = (const float*)d_in[1];
  const float* ln2 = (const float*)d_in[2];
  const float* Wq  = (const float*)d_in[3];
  const float* Wk  = (const float*)d_in[4];
  const float* Wv  = (const float*)d_in[5];
  const float* Wo  = (const float*)d_in[6];
  const float* Am  = (const float*)d_in[7];
  const float* Bm  = (const float*)d_in[8];
  const float* Win = (const float*)d_in[9];
  const float* Wup = (const float*)d_in[10];
  const float* Wdn = (const float*)d_in[11];
  float* out = (float*)d_out;
  (void)in_sizes; (void)n_in;

  const int T = 4096;
  const int Dm = 2048, F = 8192;
  const size_t MB = (size_t)1 << 20;

  const size_t need = 184 * MB;
  if (ws_size < need) {
    hipMemsetAsync(d_out, 0, (size_t)out_size * 4, stream);
    return;
  }
  char* base = (char*)d_ws;
  unsigned short* tb    = (unsigned short*)(base);
  unsigned short* wqkv  = (unsigned short*)(base);
  unsigned short* vT    = (unsigned short*)(base);
  unsigned short* xb    = (unsigned short*)(base + 24 * MB);
  unsigned short* attnO = (unsigned short*)(base + 40 * MB);
  unsigned short* qkv   = (unsigned short*)(base + 64 * MB);
  unsigned short* win   = (unsigned short*)(base + 64 * MB);
  unsigned short* wo    = (unsigned short*)(base + 112 * MB);
  unsigned short* hb    = (unsigned short*)(base + 120 * MB);
  unsigned short* attn  = (unsigned short*)(base + 136 * MB);
  float*          cv    = (float*)(base + 136 * MB);
  unsigned short* wup   = (unsigned short*)(base + 152 * MB);
  unsigned short* wdn   = (unsigned short*)(base + 152 * MB);

  cvt_f32_bf16<<<2048, 256, 0, stream>>>(Wq, wqkv, Dm * Dm / 4);
  cvt_f32_bf16<<<2048, 256, 0, stream>>>(Wk, wqkv + (size_t)Dm * Dm, Dm * Dm / 4);
  cvt_f32_bf16<<<2048, 256, 0, stream>>>(Wv, wqkv + (size_t)2 * Dm * Dm, Dm * Dm / 4);
  cvt_f32_bf16<<<2048, 256, 0, stream>>>(Wo, wo, Dm * Dm / 4);
  rmsnorm_dual<<<T, 256, 0, stream>>>(hs, ln1, ln2, xb, hb);

  // QKV projection: 16 x 48 = 768 blocks (3 exact rounds)
  gemm_n128<E_NONE><<<(T / 256) * (3 * Dm / 128), 512, 0, stream>>>(
      xb, wqkv, 3 * Dm, Dm, Dm / 64, qkv, nullptr, nullptr);

  vtrans<<<dim3(32, 2, 32), 256, 0, stream>>>(qkv, vT);
  attn_fwd2<<<dim3(16, 32), 256, 0, stream>>>(qkv, vT, attn);

  // O projection: 16 x 16 = 256 blocks (1 exact round)
  gemm_n128<E_NONE><<<(T / 256) * (Dm / 128), 512, 0, stream>>>(
      attn, wo, Dm, Dm, Dm / 64, attnO, nullptr, nullptr);

  modc<<<T / 4, 256, 0, stream>>>(attnO, hb, Am, cv);

  cvt_f32_bf16<<<2048, 256, 0, stream>>>(Win, win, F * Dm / 4);
  cvt_f32_bf16<<<2048, 256, 0, stream>>>(Wup, wup, F * Dm / 4);

  // fused gate/up: concat-B 256^2 8-phase, 16 x 64 = 1024 blocks (4 exact rounds)
  gemm_mlp256<<<(T / 256) * (F / 128), 512, 0, stream>>>(hb, win, wup, cv, Bm, tb);

  cvt_f32_bf16<<<2048, 256, 0, stream>>>(Wdn, wdn, Dm * F / 4);
  // down + residual: 16 x 16 = 256 blocks (1 exact round), K=8192
  gemm_n128<E_RES><<<(T / 256) * (Dm / 128), 512, 0, stream>>>(
      tb, wdn, Dm, F, F / 64, nullptr, out, hs);
}